// Round 6
// baseline (135.392 us; speedup 1.0000x reference)
//
#include <hip/hip_runtime.h>
#include <hip/hip_bf16.h>

#define ETA_C  0.1f
#define BETA_C 0.05f
#define MU_C   0.05f
#define MINI_C 1e-6f

// ---------- DPP wave-64 sum ----------
template<int CTRL, int ROWMASK>
__device__ __forceinline__ float dpp_add(float x) {
  int v = __builtin_amdgcn_update_dpp(0, __float_as_int(x), CTRL, ROWMASK, 0xf, true);
  return x + __int_as_float(v);
}

__device__ __forceinline__ float wave_sum(float x) {
  x = dpp_add<0xB1,  0xF>(x);
  x = dpp_add<0x4E,  0xF>(x);
  x = dpp_add<0x141, 0xF>(x);
  x = dpp_add<0x140, 0xF>(x);
  x = dpp_add<0x142, 0xA>(x);
  x = dpp_add<0x143, 0xC>(x);
  return __int_as_float(__builtin_amdgcn_readlane(__float_as_int(x), 63));
}

__device__ __forceinline__ float rl(float x, int k) {
  return __int_as_float(__builtin_amdgcn_readlane(__float_as_int(x), k));
}

// ---------- kernel A: per-block column-sum partials (no atomics, no memset) --
// 64 blocks x 256 threads. Block j sums its V-slice of seeds/exp_s/exp_n into
// part[j*192 + i] with plain stores. Blocks 0..16 also zero the atomic
// destinations in d_out (stream order: completes before main_kernel starts).
__global__ __launch_bounds__(256) void sums_kernel(
    const float* __restrict__ seeds, const float* __restrict__ es,
    const float* __restrict__ en, float* __restrict__ part,
    float* __restrict__ out, int V, int rows_per_block, int gsr_off) {
  __shared__ float sh[192];
  int t = threadIdx.x, bx = blockIdx.x;
  if (bx < 16) out[(bx << 8) + t] = 0.f;          // temp_exp_m accumulators
  else if (bx == 16 && t < 65) out[gsr_off + t] = 0.f;  // gsr + qz
  if (t < 192) sh[t] = 0.f;
  __syncthreads();
  int k = t & 63, w = t >> 6;
  int v0 = bx * rows_per_block;
  int v1 = min(v0 + rows_per_block, V);
  float s0 = 0.f, s1 = 0.f, s2 = 0.f;
  for (int v = v0 + w; v < v1; v += 4) {
    int idx = (v << 6) + k;
    s0 += seeds[idx]; s1 += es[idx]; s2 += en[idx];
  }
  atomicAdd(&sh[k], s0);        // 12 LDS atomics per block — negligible
  atomicAdd(&sh[64 + k], s1);
  atomicAdd(&sh[128 + k], s2);
  __syncthreads();
  if (t < 192) part[bx * 192 + t] = sh[t];
}

// ---------- kernel B: main per-(v) wave kernel ----------
// __launch_bounds__(1024, 4): VGPR cap 128 — avoids the R4 64-VGPR spill cliff.
__global__ __launch_bounds__(1024, 4) void main_kernel(
    const float* __restrict__ bow,   // (B=64, V)
    const float* __restrict__ seeds, // (V, 64)
    const float* __restrict__ exp_m, // (64, 64)
    const float* __restrict__ exp_s, // (V, 64)
    const float* __restrict__ exp_n, // (V, 64)
    const float* __restrict__ pi,    // (64)
    const float* __restrict__ part,  // 64 x 192 partials from sums_kernel
    float* __restrict__ out, int V, int gsr_off) {
  __shared__ float theta_lds[4096];       // theta[b*64+k]
  __shared__ float thetaT_lds[64 * 65];   // theta[k*65+b]  (padded)
  __shared__ float sums_sh[192];          // [S | exp_s_sum | exp_n_sum]
  __shared__ float wsL[1024];             // per-wave w_s[v,k]   (lane=k)
  __shared__ float wrL[1024];             // per-wave w_r[v,k]   (lane=k)
  __shared__ float cisL[1024];            // per-wave c*inv_s[b] (lane=b)
  __shared__ float cirL[1024];            // per-wave c*inv_r[b] (lane=b)
  __shared__ float red_gsr[1024];
  __shared__ float red_qz[16];

  int t = threadIdx.x;
#pragma unroll
  for (int i = 0; i < 4; i++) {
    int idx = t + i * 1024;
    float val = exp_m[idx] + ETA_C;
    theta_lds[idx] = val;
    thetaT_lds[(idx & 63) * 65 + (idx >> 6)] = val;
  }
  if (t < 192) {   // reduce the 64 column-sum partials (L2-resident)
    float s = 0.f;
#pragma unroll 8
    for (int j = 0; j < 64; j++) s += part[j * 192 + t];
    sums_sh[t] = s;
  }
  __syncthreads();

  int lane = t & 63, w = t >> 6;
  int v = blockIdx.x * 16 + w;
  bool active = (v < V);

  float acc_n = 0.f, acc_s = 0.f, acc_g = 0.f, acc_q = 0.f;
  float ivx = 0.f, ivy = 0.f, bowpre = 0.f;
  float a_ss = 0.f, a_sr = 0.f, a_rr = 0.f, pik = 0.f, omp = 0.f;
  unsigned long long m = 0ull;
  bool seedRow = false;

  if (active) {
    int rbase = (v << 6) + lane;
    float seed = seeds[rbase];
    float es = exp_s[rbase];
    float en = exp_n[rbase];
    pik = pi[lane];
    float Sk = sums_sh[lane];
    float essum = sums_sh[64 + lane];
    float ensum = sums_sh[128 + lane];
    float inv_ds = __builtin_amdgcn_rcpf(MU_C * Sk + essum);
    float inv_dn = __builtin_amdgcn_rcpf(BETA_C * (float)V + ensum);
    float phi_s = (MU_C + es) * inv_ds;
    float phi_n = (BETA_C + en) * inv_dn;
    omp = 1.0f - pik;
    a_ss = seed * phi_s * pik;            // lane = k
    a_sr = seed * phi_n * omp;
    a_rr = (1.0f - seed) * phi_n;
    seedRow = (__ballot(seed > 0.f) != 0ull);

    wsL[(w << 6) + lane] = fmaf(pik, a_ss, omp * a_sr);
    wrL[(w << 6) + lane] = seedRow ? omp * a_rr : a_rr;

    bowpre = bow[lane * V + v];           // lane = b
    m = __ballot(bowpre > 0.f);

    // ---- phase 1 (lane = b): matvec for s_sum / r_sum ----
    float asv = a_ss + a_sr;
    float ss = 0.f, rs = 0.f;
    if (seedRow) {
#pragma unroll 8
      for (int k = 0; k < 64; k++) {
        float th = thetaT_lds[k * 65 + lane];
        ss = fmaf(th, rl(asv, k), ss);
        rs = fmaf(th, rl(a_rr, k), rs);
      }
    } else {
#pragma unroll 8
      for (int k = 0; k < 64; k++) {
        float th = thetaT_lds[k * 65 + lane];
        rs = fmaf(th, rl(a_rr, k), rs);
      }
    }
    ivx = __builtin_amdgcn_rcpf(ss + MINI_C);
    ivy = __builtin_amdgcn_rcpf(rs + MINI_C);
    cisL[(w << 6) + lane] = bowpre * ivx;
    cirL[(w << 6) + lane] = bowpre * ivy;
  } else {
    wsL[(w << 6) + lane] = 0.f;
    wrL[(w << 6) + lane] = 0.f;
    cisL[(w << 6) + lane] = 0.f;
    cirL[(w << 6) + lane] = 0.f;
  }
  __syncthreads();

  // ---- phase 2 (lane = k): per active b, register-only accumulation ----
  if (active) {
    int rbase = (v << 6) + lane;
    if (seedRow) {
      while (m) {
        int b = __builtin_ctzll(m);
        m &= (m - 1);
        float cb = rl(bowpre, b);
        float is = rl(ivx, b), ir = rl(ivy, b);
        float th = theta_lds[(b << 6) + lane];
        float gss = th * a_ss * is;
        float gsr = th * a_sr * is;
        float grr = th * a_rr * ir;
        float gnr = gsr + grr;
        float gamma = fmaf(pik, gss, omp * gnr);
        acc_n = fmaf(gnr, cb, acc_n);
        acc_s = fmaf(gss, cb, acc_s);
        acc_g += gsr;
        acc_q = fmaf(gamma, __logf(gamma + MINI_C), acc_q);
      }
    } else {
      while (m) {
        int b = __builtin_ctzll(m);
        m &= (m - 1);
        float cb = rl(bowpre, b);
        float ir = rl(ivy, b);
        float th = theta_lds[(b << 6) + lane];
        float grr = th * a_rr * ir;           // gamma == grr
        acc_n = fmaf(grr, cb, acc_n);
        acc_q = fmaf(grr, __logf(grr + MINI_C), acc_q);
      }
    }
    out[4096 + rbase] = acc_n;            // temp_exp_n
    out[4096 + V * 64 + rbase] = acc_s;   // temp_exp_s
  }

  // ---- phase 2b (lane = k): block outer-product partial for temp_exp_m ----
  {
    float acc4x = 0.f, acc4y = 0.f, acc4z = 0.f, acc4w = 0.f;
#pragma unroll 4
    for (int u = 0; u < 16; u++) {
      float wsu = wsL[(u << 6) + lane];
      float wru = wrL[(u << 6) + lane];
      float4 c4 = *(const float4*)&cisL[(u << 6) + (w << 2)];  // broadcast
      float4 r4 = *(const float4*)&cirL[(u << 6) + (w << 2)];
      acc4x = fmaf(c4.x, wsu, fmaf(r4.x, wru, acc4x));
      acc4y = fmaf(c4.y, wsu, fmaf(r4.y, wru, acc4y));
      acc4z = fmaf(c4.z, wsu, fmaf(r4.z, wru, acc4z));
      acc4w = fmaf(c4.w, wsu, fmaf(r4.w, wru, acc4w));
    }
    float av[4] = {acc4x, acc4y, acc4z, acc4w};
#pragma unroll
    for (int j = 0; j < 4; j++) {
      int b = (w << 2) + j;
      float val = av[j] * theta_lds[(b << 6) + lane];
      atomicAdd(&out[(b << 6) + lane], val);   // zeroed by sums_kernel
    }
  }

  red_gsr[(w << 6) | lane] = acc_g;
  float qz_w = wave_sum(acc_q);
  if (lane == 0) red_qz[w] = qz_w;
  __syncthreads();

  if (w == 0) {
    float g = 0.f;
#pragma unroll
    for (int j = 0; j < 16; j++) g += red_gsr[(j << 6) | lane];
    atomicAdd(&out[gsr_off + lane], g);
    if (t == 0) {
      float q = 0.f;
#pragma unroll
      for (int j = 0; j < 16; j++) q += red_qz[j];
      atomicAdd(&out[gsr_off + 64], q);
    }
  }
}

extern "C" void kernel_launch(void* const* d_in, const int* in_sizes, int n_in,
                              void* d_out, int out_size, void* d_ws,
                              size_t ws_size, hipStream_t stream) {
  (void)n_in; (void)out_size; (void)ws_size;
  const float* bow   = (const float*)d_in[0];
  const float* seeds = (const float*)d_in[1];
  const float* exp_m = (const float*)d_in[2];
  const float* exp_s = (const float*)d_in[3];
  const float* exp_n = (const float*)d_in[4];
  const float* pi    = (const float*)d_in[5];
  int K = in_sizes[5];          // 64
  int V = in_sizes[1] / K;      // 10000
  float* out = (float*)d_out;
  float* part = (float*)d_ws;   // 64 x 192 floats = 48 KB

  int NB = (V + 15) / 16;       // 625 blocks, 16 waves (one v each)
  int gsr_off = 4096 + 2 * V * 64;
  int rpb = (V + 63) / 64;      // 157

  sums_kernel<<<64, 256, 0, stream>>>(seeds, exp_s, exp_n, part, out, V, rpb,
                                      gsr_off);
  main_kernel<<<NB, 1024, 0, stream>>>(bow, seeds, exp_m, exp_s, exp_n, pi,
                                       part, out, V, gsr_off);
}

// Round 7
// 128.224 us; speedup vs baseline: 1.0559x; 1.0559x over previous
//
#include <hip/hip_runtime.h>
#include <hip/hip_bf16.h>

#define ETA_C  0.1f
#define BETA_C 0.05f
#define MU_C   0.05f
#define MINI_C 1e-6f

// ---------- DPP wave-64 sum ----------
template<int CTRL, int ROWMASK>
__device__ __forceinline__ float dpp_add(float x) {
  int v = __builtin_amdgcn_update_dpp(0, __float_as_int(x), CTRL, ROWMASK, 0xf, true);
  return x + __int_as_float(v);
}

__device__ __forceinline__ float wave_sum(float x) {
  x = dpp_add<0xB1,  0xF>(x);
  x = dpp_add<0x4E,  0xF>(x);
  x = dpp_add<0x141, 0xF>(x);
  x = dpp_add<0x140, 0xF>(x);
  x = dpp_add<0x142, 0xA>(x);
  x = dpp_add<0x143, 0xC>(x);
  return __int_as_float(__builtin_amdgcn_readlane(__float_as_int(x), 63));
}

__device__ __forceinline__ float rl(float x, int k) {
  return __int_as_float(__builtin_amdgcn_readlane(__float_as_int(x), k));
}

// ---------- kernel A: per-block column-sum partials ----------
// 64 blocks x 256 threads -> part[bx*192 + i], plain stores (no memset needed).
// If the ws fallback is active, also zero the atomic destinations in out.
__global__ __launch_bounds__(256) void sums_kernel(
    const float* __restrict__ seeds, const float* __restrict__ es,
    const float* __restrict__ en, float* __restrict__ part,
    float* __restrict__ out, int V, int rows_per_block, int gsr_off,
    int zeroOut) {
  __shared__ float sh[192];
  int t = threadIdx.x, bx = blockIdx.x;
  if (zeroOut) {
    if (bx < 16) out[(bx << 8) + t] = 0.f;
    else if (bx == 16 && t < 65) out[gsr_off + t] = 0.f;
  }
  if (t < 192) sh[t] = 0.f;
  __syncthreads();
  int k = t & 63, w = t >> 6;
  int v0 = bx * rows_per_block;
  int v1 = min(v0 + rows_per_block, V);
  float s0 = 0.f, s1 = 0.f, s2 = 0.f;
  for (int v = v0 + w; v < v1; v += 4) {
    int idx = (v << 6) + k;
    s0 += seeds[idx]; s1 += es[idx]; s2 += en[idx];
  }
  atomicAdd(&sh[k], s0);
  atomicAdd(&sh[64 + k], s1);
  atomicAdd(&sh[128 + k], s2);
  __syncthreads();
  if (t < 192) part[bx * 192 + t] = sh[t];
}

// ---------- kernel B: main per-(v) wave kernel ----------
__global__ __launch_bounds__(1024, 4) void main_kernel(
    const float* __restrict__ bow,   // (B=64, V)
    const float* __restrict__ seeds, // (V, 64)
    const float* __restrict__ exp_m, // (64, 64)
    const float* __restrict__ exp_s, // (V, 64)
    const float* __restrict__ exp_n, // (V, 64)
    const float* __restrict__ pi,    // (64)
    const float* __restrict__ part,  // 64 x 192 column-sum partials
    float* __restrict__ out,
    float* __restrict__ wsm, float* __restrict__ wsgq,
    int V, int useWs, int gsr_off) {
  __shared__ float2 thP[4096];         // {th, th*ln th}   [b*64+k]   32 KB
  __shared__ unsigned int thTu[2048];  // bf16 th pairs    [(k>>1)*64+b] 8 KB
  __shared__ float4 stage[1024];       // [w*64+i] .x=ws .y=wr .z=asv->cis .w=cir
  __shared__ float sums_sh[192];       // [S | exp_s_sum | exp_n_sum]
  __shared__ float red_gsr[1024];
  __shared__ float redq[16];

  int t = threadIdx.x;
#pragma unroll
  for (int i = 0; i < 4; i++) {
    int idx = t + (i << 10);
    float th = exp_m[idx] + ETA_C;
    float lth = __logf(th);
    thP[idx] = make_float2(th, th * lth);
    unsigned u = __float_as_uint(th);
    u += 0x7fffu + ((u >> 16) & 1u);                 // round-to-nearest bf16
    int k = idx & 63, b = idx >> 6;
    reinterpret_cast<unsigned short*>(thTu)[((k >> 1) << 7) + (b << 1) + (k & 1)]
        = (unsigned short)(u >> 16);
  }
  if (t < 192) {
    float s = 0.f;
#pragma unroll 8
    for (int j = 0; j < 64; j++) s += part[j * 192 + t];
    sums_sh[t] = s;
  }
  __syncthreads();

  int lane = t & 63, w = t >> 6;
  int v = (blockIdx.x << 4) + w;
  bool active = (v < V);
  int sbase = (w << 6);

  float acc_n = 0.f, acc_s = 0.f, acc_g = 0.f, acc_q = 0.f;
  float pik = 0.f, omp = 0.f, a_ss = 0.f, a_sr = 0.f, a_rr = 0.f;
  float bowpre = 0.f, ivx = 0.f, ivy = 0.f, q0 = 0.f, q1 = 0.f, cirr = 0.f;
  bool seedRow = false;

  if (active) {
    int rbase = (v << 6) + lane;
    float seed = seeds[rbase];
    float es = exp_s[rbase];
    float en = exp_n[rbase];
    pik = pi[lane];
    float inv_ds = __builtin_amdgcn_rcpf(MU_C * sums_sh[lane] + sums_sh[64 + lane]);
    float inv_dn = __builtin_amdgcn_rcpf(BETA_C * (float)V + sums_sh[128 + lane]);
    float phi_s = (MU_C + es) * inv_ds;
    float phi_n = (BETA_C + en) * inv_dn;
    omp = 1.0f - pik;
    a_ss = seed * phi_s * pik;            // lane = k
    a_sr = seed * phi_n * omp;
    a_rr = (1.0f - seed) * phi_n;
    seedRow = (__ballot(seed > 0.f) != 0ull);
    float wsv = fmaf(pik, a_ss, omp * a_sr);
    float wrv = seedRow ? omp * a_rr : a_rr;
    stage[sbase + lane] = make_float4(wsv, wrv, a_ss + a_sr, 0.f);
    bowpre = bow[lane * V + v];           // lane = b

    // ---- phase 1 (lane = b): rs/ss matvec over k, bf16 theta^T pairs ----
    float rs = 0.f, ss = 0.f;
    if (seedRow) {
      float asv = a_ss + a_sr;
#pragma unroll 8
      for (int k2 = 0; k2 < 32; k2++) {
        unsigned pp = thTu[(k2 << 6) + lane];
        float te = __uint_as_float(pp << 16);
        float to = __uint_as_float(pp & 0xffff0000u);
        ss = fmaf(te, rl(asv, 2 * k2), ss);
        ss = fmaf(to, rl(asv, 2 * k2 + 1), ss);
        rs = fmaf(te, rl(a_rr, 2 * k2), rs);
        rs = fmaf(to, rl(a_rr, 2 * k2 + 1), rs);
      }
    } else {
#pragma unroll 8
      for (int k2 = 0; k2 < 32; k2++) {
        unsigned pp = thTu[(k2 << 6) + lane];
        float te = __uint_as_float(pp << 16);
        float to = __uint_as_float(pp & 0xffff0000u);
        rs = fmaf(te, stage[sbase + 2 * k2].y, rs);      // broadcast: .y == a_rr
        rs = fmaf(to, stage[sbase + 2 * k2 + 1].y, rs);
      }
    }
    ivx = __builtin_amdgcn_rcpf(ss + MINI_C);
    ivy = __builtin_amdgcn_rcpf(rs + MINI_C);
    float lir = __logf(ivy);
    bool has = bowpre > 0.f;
    q0 = has ? ivy : 0.f;                 // mask: inactive b contribute 0
    q1 = q0 * lir;
    cirr = bowpre * ivy;
    float cis = bowpre * ivx;
    stage[sbase + lane].z = cis;
    stage[sbase + lane].w = cirr;
  } else {
    stage[sbase + lane] = make_float4(0.f, 0.f, 0.f, 0.f);
  }

  // ---- phase 2 (lane = k): own-wave registers only, pre-barrier ----
  if (active) {
    int rbase = (v << 6) + lane;
    if (!seedRow) {
      // gamma = th * a_rr * ir;  ln gamma = ln th + ln a_rr + ln ir
      float P = 0.f, Q = 0.f, R = 0.f, N = 0.f;
#pragma unroll 8
      for (int b = 0; b < 64; b++) {
        float2 tp = thP[(b << 6) + lane];
        float u0 = rl(q0, b);
        float u1 = rl(q1, b);
        float u2 = rl(cirr, b);
        P = fmaf(tp.x, u0, P);
        R = fmaf(tp.y, u0, R);
        Q = fmaf(tp.x, u1, Q);
        N = fmaf(tp.x, u2, N);
      }
      float larr = __logf(a_rr);
      acc_q = a_rr * (R + fmaf(larr, P, Q));
      acc_n = a_rr * N;
      // acc_s = 0, acc_g = 0 for non-seed rows
    } else {
      unsigned long long m = __ballot(bowpre > 0.f);
      while (m) {
        int b = __builtin_amdgcn_readfirstlane(__builtin_ctzll(m));
        m &= (m - 1);
        float cb = rl(bowpre, b);
        float is = rl(ivx, b), ir = rl(ivy, b);
        float th = thP[(b << 6) + lane].x;
        float gss = th * a_ss * is;
        float gsr = th * a_sr * is;
        float grr = th * a_rr * ir;
        float gnr = gsr + grr;
        float gamma = fmaf(pik, gss, omp * gnr);
        acc_n = fmaf(gnr, cb, acc_n);
        acc_s = fmaf(gss, cb, acc_s);
        acc_g += gsr;
        acc_q = fmaf(gamma, __logf(gamma + MINI_C), acc_q);
      }
    }
    out[4096 + rbase] = acc_n;            // temp_exp_n
    out[4096 + V * 64 + rbase] = acc_s;   // temp_exp_s
  }
  __syncthreads();   // stage ready for cross-wave phase 2b

  // ---- phase 2b (lane = k): block outer-product partial for temp_exp_m ----
  {
    float a0 = 0.f, a1 = 0.f, a2 = 0.f, a3 = 0.f;
#pragma unroll 4
    for (int u = 0; u < 16; u++) {
      float4 sv = stage[(u << 6) + lane];                    // ws, wr at lane=k
      const float* cc = (const float*)&stage[(u << 6) + (w << 2)];
      float2 c0 = *(const float2*)(cc + 2);                  // {cis,cir} b=4w
      float2 c1 = *(const float2*)(cc + 6);
      float2 c2 = *(const float2*)(cc + 10);
      float2 c3 = *(const float2*)(cc + 14);
      a0 = fmaf(c0.x, sv.x, fmaf(c0.y, sv.y, a0));
      a1 = fmaf(c1.x, sv.x, fmaf(c1.y, sv.y, a1));
      a2 = fmaf(c2.x, sv.x, fmaf(c2.y, sv.y, a2));
      a3 = fmaf(c3.x, sv.x, fmaf(c3.y, sv.y, a3));
    }
    float av[4] = {a0, a1, a2, a3};
#pragma unroll
    for (int j = 0; j < 4; j++) {
      int b = (w << 2) + j;
      float val = av[j] * thP[(b << 6) + lane].x;
      if (useWs) wsm[blockIdx.x * 4096 + (b << 6) + lane] = val;
      else atomicAdd(&out[(b << 6) + lane], val);
    }
  }

  red_gsr[t] = acc_g;
  float qzw = wave_sum(acc_q);
  if (lane == 0) redq[w] = qzw;
  __syncthreads();

  if (w == 0) {
    float g = 0.f;
#pragma unroll
    for (int j = 0; j < 16; j++) g += red_gsr[(j << 6) + lane];
    if (useWs) wsgq[blockIdx.x * 66 + lane] = g;
    else if (g != 0.f) atomicAdd(&out[gsr_off + lane], g);
    if (t == 0) {
      float q = 0.f;
#pragma unroll
      for (int j = 0; j < 16; j++) q += redq[j];
      if (useWs) wsgq[blockIdx.x * 66 + 64] = q;
      else atomicAdd(&out[gsr_off + 64], q);
    }
  }
}

// ---------- kernel C: parallel reduce of per-block partials ----------
__global__ __launch_bounds__(1024) void reduce_kernel(
    const float* __restrict__ wsm, const float* __restrict__ wsgq,
    float* __restrict__ out, int NB, int gsr_off) {
  __shared__ float sh[1024];
  int t = threadIdx.x, lane = t & 63, w = t >> 6, bx = blockIdx.x;
  if (bx < 64) {
    int e = (bx << 6) + lane;
    float s0 = 0.f, s1 = 0.f, s2 = 0.f, s3 = 0.f;
    int j = w;
    for (; j + 48 < NB; j += 64) {
      s0 += wsm[(size_t)(j)      * 4096 + e];
      s1 += wsm[(size_t)(j + 16) * 4096 + e];
      s2 += wsm[(size_t)(j + 32) * 4096 + e];
      s3 += wsm[(size_t)(j + 48) * 4096 + e];
    }
    for (; j < NB; j += 16) s0 += wsm[(size_t)j * 4096 + e];
    sh[t] = (s0 + s1) + (s2 + s3);
    __syncthreads();
    if (w == 0) {
      float tot = 0.f;
#pragma unroll
      for (int i = 0; i < 16; i++) tot += sh[(i << 6) + lane];
      out[e] = tot;
    }
  } else if (bx == 64) {
    float s = 0.f;
    for (int j = w; j < NB; j += 16) s += wsgq[j * 66 + lane];
    sh[t] = s;
    __syncthreads();
    if (w == 0) {
      float tot = 0.f;
#pragma unroll
      for (int i = 0; i < 16; i++) tot += sh[(i << 6) + lane];
      out[gsr_off + lane] = tot;
    }
  } else {
    float s = 0.f;
    for (int j = t; j < NB; j += 1024) s += wsgq[j * 66 + 64];
    s = wave_sum(s);
    if (lane == 0) sh[w] = s;
    __syncthreads();
    if (t == 0) {
      float tot = 0.f;
#pragma unroll
      for (int i = 0; i < 16; i++) tot += sh[i];
      out[gsr_off + 64] = tot;
    }
  }
}

extern "C" void kernel_launch(void* const* d_in, const int* in_sizes, int n_in,
                              void* d_out, int out_size, void* d_ws,
                              size_t ws_size, hipStream_t stream) {
  (void)n_in; (void)out_size;
  const float* bow   = (const float*)d_in[0];
  const float* seeds = (const float*)d_in[1];
  const float* exp_m = (const float*)d_in[2];
  const float* exp_s = (const float*)d_in[3];
  const float* exp_n = (const float*)d_in[4];
  const float* pi    = (const float*)d_in[5];
  int K = in_sizes[5];          // 64
  int V = in_sizes[1] / K;      // 10000
  float* out = (float*)d_out;
  float* ws = (float*)d_ws;

  int NB = (V + 15) / 16;       // 625 blocks, 16 waves (one v each)
  int gsr_off = 4096 + 2 * V * 64;

  size_t needF = (size_t)NB * 4096 + (size_t)NB * 66 + 64 * 192;
  int useWs = (ws_size >= needF * 4) ? 1 : 0;

  float* wsm  = ws;                          // NB x 4096
  float* wsgq = wsm + (size_t)NB * 4096;     // NB x 66 (gsr 64 + qz)
  float* part = wsgq + (size_t)NB * 66;      // 64 x 192

  int rpb = (V + 63) / 64;
  sums_kernel<<<64, 256, 0, stream>>>(seeds, exp_s, exp_n, part, out, V, rpb,
                                      gsr_off, useWs ? 0 : 1);
  main_kernel<<<NB, 1024, 0, stream>>>(bow, seeds, exp_m, exp_s, exp_n, pi,
                                       part, out, wsm, wsgq, V, useWs, gsr_off);
  if (useWs) {
    reduce_kernel<<<66, 1024, 0, stream>>>(wsm, wsgq, out, NB, gsr_off);
  }
}

// Round 8
// 124.866 us; speedup vs baseline: 1.0843x; 1.0269x over previous
//
#include <hip/hip_runtime.h>
#include <hip/hip_bf16.h>

#define ETA_C  0.1f
#define BETA_C 0.05f
#define MU_C   0.05f
#define MINI_C 1e-6f

// ---------- DPP wave-64 sum ----------
template<int CTRL, int ROWMASK>
__device__ __forceinline__ float dpp_add(float x) {
  int v = __builtin_amdgcn_update_dpp(0, __float_as_int(x), CTRL, ROWMASK, 0xf, true);
  return x + __int_as_float(v);
}

__device__ __forceinline__ float wave_sum(float x) {
  x = dpp_add<0xB1,  0xF>(x);
  x = dpp_add<0x4E,  0xF>(x);
  x = dpp_add<0x141, 0xF>(x);
  x = dpp_add<0x140, 0xF>(x);
  x = dpp_add<0x142, 0xA>(x);
  x = dpp_add<0x143, 0xC>(x);
  return __int_as_float(__builtin_amdgcn_readlane(__float_as_int(x), 63));
}

__device__ __forceinline__ float rl(float x, int k) {
  return __int_as_float(__builtin_amdgcn_readlane(__float_as_int(x), k));
}

__device__ __forceinline__ unsigned short bf16r(float x) {
  unsigned u = __float_as_uint(x);
  u += 0x7fffu + ((u >> 16) & 1u);
  return (unsigned short)(u >> 16);
}

// ---------- kernel A: per-block column-sum partials ----------
__global__ __launch_bounds__(256) void sums_kernel(
    const float* __restrict__ seeds, const float* __restrict__ es,
    const float* __restrict__ en, float* __restrict__ part,
    float* __restrict__ out, int V, int rows_per_block, int gsr_off,
    int zeroOut) {
  __shared__ float sh[192];
  int t = threadIdx.x, bx = blockIdx.x;
  if (zeroOut) {
    if (bx < 16) out[(bx << 8) + t] = 0.f;
    else if (bx == 16 && t < 65) out[gsr_off + t] = 0.f;
  }
  if (t < 192) sh[t] = 0.f;
  __syncthreads();
  int k = t & 63, w = t >> 6;
  int v0 = bx * rows_per_block;
  int v1 = min(v0 + rows_per_block, V);
  float s0 = 0.f, s1 = 0.f, s2 = 0.f;
  for (int v = v0 + w; v < v1; v += 4) {
    int idx = (v << 6) + k;
    s0 += seeds[idx]; s1 += es[idx]; s2 += en[idx];
  }
  atomicAdd(&sh[k], s0);
  atomicAdd(&sh[64 + k], s1);
  atomicAdd(&sh[128 + k], s2);
  __syncthreads();
  if (t < 192) part[bx * 192 + t] = sh[t];
}

// ---------- kernel B: main per-(v) wave kernel ----------
__global__ __launch_bounds__(1024, 4) void main_kernel(
    const float* __restrict__ bow,   // (B=64, V)
    const float* __restrict__ seeds, // (V, 64)
    const float* __restrict__ exp_m, // (64, 64)
    const float* __restrict__ exp_s, // (V, 64)
    const float* __restrict__ exp_n, // (V, 64)
    const float* __restrict__ pi,    // (64)
    const float* __restrict__ part,  // 64 x 192 column-sum partials
    float* __restrict__ out,
    float* __restrict__ wsm, float* __restrict__ wsgq,
    int V, int useWs, int gsr_off) {
  __shared__ float thF[4096];          // th fp32            [b*64+k]  16 KB
  __shared__ unsigned int thTu[2048];  // bf16 th^T pairs    [(k>>1)*64+b] 8 KB
  __shared__ unsigned int tlTu[2048];  // bf16 (th lnth)^T   [(k>>1)*64+b] 8 KB
  __shared__ float wsA[1024];          // per-wave w_s[v,k]  (lane=k)   4 KB
  __shared__ float wrA[1024];          // per-wave w_r[v,k]  (lane=k)   4 KB
  __shared__ float2 cpair[1024];       // per-wave {cis,cir} (lane=b)   8 KB
  __shared__ float sums_sh[192];
  __shared__ float red_gsr[1024];
  __shared__ float redq[16];

  int t = threadIdx.x;
#pragma unroll
  for (int i = 0; i < 4; i++) {
    int idx = t + (i << 10);
    float th = exp_m[idx] + ETA_C;
    float lth = __logf(th);
    thF[idx] = th;
    int k = idx & 63, b = idx >> 6;
    int pos = ((k >> 1) << 7) + (b << 1) + (k & 1);
    reinterpret_cast<unsigned short*>(thTu)[pos] = bf16r(th);
    reinterpret_cast<unsigned short*>(tlTu)[pos] = bf16r(th * lth);
  }
  if (t < 192) {
    float s = 0.f;
#pragma unroll 8
    for (int j = 0; j < 64; j++) s += part[j * 192 + t];
    sums_sh[t] = s;
  }
  __syncthreads();

  int lane = t & 63, w = t >> 6;
  int v = (blockIdx.x << 4) + w;
  bool active = (v < V);
  int sbase = (w << 6);

  float acc_s = 0.f, acc_g = 0.f, acc_qk = 0.f, acc_qb = 0.f;
  bool seedRow = false;

  if (active) {
    int rbase = (v << 6) + lane;
    float seed = seeds[rbase];
    float es = exp_s[rbase];
    float en = exp_n[rbase];
    float pik = pi[lane];
    float inv_ds = __builtin_amdgcn_rcpf(MU_C * sums_sh[lane] + sums_sh[64 + lane]);
    float inv_dn = __builtin_amdgcn_rcpf(BETA_C * (float)V + sums_sh[128 + lane]);
    float phi_s = (MU_C + es) * inv_ds;
    float phi_n = (BETA_C + en) * inv_dn;
    float omp = 1.0f - pik;
    float a_ss = seed * phi_s * pik;      // lane = k
    float a_sr = seed * phi_n * omp;
    float a_rr = (1.0f - seed) * phi_n;
    seedRow = (__ballot(seed > 0.f) != 0ull);
    wsA[sbase + lane] = fmaf(pik, a_ss, omp * a_sr);
    wrA[sbase + lane] = seedRow ? omp * a_rr : a_rr;
    float bowpre = bow[lane * V + v];     // lane = b

    float acc_n = 0.f;
    if (!seedRow) {
      // ---- phase 1 (lane=b): rs + L GEMVs over k (bf16 pairs) ----
      float arrl = a_rr * __logf(a_rr);   // lane = k scalar source
      float rs = 0.f, L = 0.f;
#pragma unroll 8
      for (int k2 = 0; k2 < 32; k2++) {
        unsigned pt = thTu[(k2 << 6) + lane];
        unsigned pl = tlTu[(k2 << 6) + lane];
        float te = __uint_as_float(pt << 16);
        float to = __uint_as_float(pt & 0xffff0000u);
        float le = __uint_as_float(pl << 16);
        float lo = __uint_as_float(pl & 0xffff0000u);
        float ae = rl(a_rr, 2 * k2), ao = rl(a_rr, 2 * k2 + 1);
        rs = fmaf(te, ae, rs);
        rs = fmaf(to, ao, rs);
        L = fmaf(le, ae, L);
        L = fmaf(lo, ao, L);
        L = fmaf(te, rl(arrl, 2 * k2), L);
        L = fmaf(to, rl(arrl, 2 * k2 + 1), L);
      }
      float ivy = __builtin_amdgcn_rcpf(rs + MINI_C);
      float q0 = (bowpre > 0.f) ? ivy : 0.f;
      float q1 = q0 * __logf(ivy);
      float cirr = bowpre * ivy;
      acc_qb += fmaf(q0, L, q1 * rs);     // lane = b accumulator
      cpair[sbase + lane] = make_float2(bowpre * 1e6f /*unused: ws=0*/ * 0.f, cirr);

      // ---- phase 2 (lane=k): N GEMV over b ----
      float N = 0.f;
#pragma unroll 8
      for (int b = 0; b < 64; b++)
        N = fmaf(thF[(b << 6) + lane], rl(cirr, b), N);
      acc_n = a_rr * N;
    } else {
      // ---- seed row: exact path ----
      float asv = a_ss + a_sr;
      float rs = 0.f, ss = 0.f;
#pragma unroll 8
      for (int k2 = 0; k2 < 32; k2++) {
        unsigned pt = thTu[(k2 << 6) + lane];
        float te = __uint_as_float(pt << 16);
        float to = __uint_as_float(pt & 0xffff0000u);
        ss = fmaf(te, rl(asv, 2 * k2), ss);
        ss = fmaf(to, rl(asv, 2 * k2 + 1), ss);
        rs = fmaf(te, rl(a_rr, 2 * k2), rs);
        rs = fmaf(to, rl(a_rr, 2 * k2 + 1), rs);
      }
      float ivx = __builtin_amdgcn_rcpf(ss + MINI_C);
      float ivy = __builtin_amdgcn_rcpf(rs + MINI_C);
      cpair[sbase + lane] = make_float2(bowpre * ivx, bowpre * ivy);
      unsigned long long m = __ballot(bowpre > 0.f);
      while (m) {
        int b = __builtin_amdgcn_readfirstlane(__builtin_ctzll(m));
        m &= (m - 1);
        float cb = rl(bowpre, b);
        float is = rl(ivx, b), ir = rl(ivy, b);
        float th = thF[(b << 6) + lane];
        float gss = th * a_ss * is;
        float gsr = th * a_sr * is;
        float grr = th * a_rr * ir;
        float gnr = gsr + grr;
        float gamma = fmaf(pik, gss, omp * gnr);
        acc_n = fmaf(gnr, cb, acc_n);
        acc_s = fmaf(gss, cb, acc_s);
        acc_g += gsr;
        acc_qk = fmaf(gamma, __logf(gamma + MINI_C), acc_qk);
      }
    }
    out[4096 + rbase] = acc_n;            // temp_exp_n
    out[4096 + V * 64 + rbase] = acc_s;   // temp_exp_s
  } else {
    wsA[sbase + lane] = 0.f;
    wrA[sbase + lane] = 0.f;
    cpair[sbase + lane] = make_float2(0.f, 0.f);
  }
  __syncthreads();   // stage ready for cross-wave phase 2b

  // ---- phase 2b (lane=k): block outer-product partial for temp_exp_m ----
  {
    const float4* cp4 = reinterpret_cast<const float4*>(cpair);
    float a0 = 0.f, a1 = 0.f, a2 = 0.f, a3 = 0.f;
#pragma unroll 4
    for (int u = 0; u < 16; u++) {
      float a_ws = wsA[(u << 6) + lane];
      float a_wr = wrA[(u << 6) + lane];
      float4 c01 = cp4[(u << 5) + (w << 1)];      // b=4w,4w+1: {cis,cir}x2
      float4 c23 = cp4[(u << 5) + (w << 1) + 1];  // b=4w+2,4w+3
      a0 = fmaf(c01.x, a_ws, fmaf(c01.y, a_wr, a0));
      a1 = fmaf(c01.z, a_ws, fmaf(c01.w, a_wr, a1));
      a2 = fmaf(c23.x, a_ws, fmaf(c23.y, a_wr, a2));
      a3 = fmaf(c23.z, a_ws, fmaf(c23.w, a_wr, a3));
    }
    float av[4] = {a0, a1, a2, a3};
#pragma unroll
    for (int j = 0; j < 4; j++) {
      int b = (w << 2) + j;
      float val = av[j] * thF[(b << 6) + lane];
      if (useWs) wsm[blockIdx.x * 4096 + (b << 6) + lane] = val;
      else atomicAdd(&out[(b << 6) + lane], val);
    }
  }

  red_gsr[t] = acc_g;
  float qzw = wave_sum(acc_qk + acc_qb);
  if (lane == 0) redq[w] = qzw;
  __syncthreads();

  if (w == 0) {
    float g = 0.f;
#pragma unroll
    for (int j = 0; j < 16; j++) g += red_gsr[(j << 6) + lane];
    if (useWs) wsgq[blockIdx.x * 66 + lane] = g;
    else if (g != 0.f) atomicAdd(&out[gsr_off + lane], g);
    if (t == 0) {
      float q = 0.f;
#pragma unroll
      for (int j = 0; j < 16; j++) q += redq[j];
      if (useWs) wsgq[blockIdx.x * 66 + 64] = q;
      else atomicAdd(&out[gsr_off + 64], q);
    }
  }
}

// ---------- kernel C: parallel reduce of per-block partials ----------
__global__ __launch_bounds__(1024) void reduce_kernel(
    const float* __restrict__ wsm, const float* __restrict__ wsgq,
    float* __restrict__ out, int NB, int gsr_off) {
  __shared__ float sh[1024];
  int t = threadIdx.x, lane = t & 63, w = t >> 6, bx = blockIdx.x;
  if (bx < 64) {
    int e = (bx << 6) + lane;
    float s0 = 0.f, s1 = 0.f, s2 = 0.f, s3 = 0.f;
    int j = w;
    for (; j + 48 < NB; j += 64) {
      s0 += wsm[(size_t)(j)      * 4096 + e];
      s1 += wsm[(size_t)(j + 16) * 4096 + e];
      s2 += wsm[(size_t)(j + 32) * 4096 + e];
      s3 += wsm[(size_t)(j + 48) * 4096 + e];
    }
    for (; j < NB; j += 16) s0 += wsm[(size_t)j * 4096 + e];
    sh[t] = (s0 + s1) + (s2 + s3);
    __syncthreads();
    if (w == 0) {
      float tot = 0.f;
#pragma unroll
      for (int i = 0; i < 16; i++) tot += sh[(i << 6) + lane];
      out[e] = tot;
    }
  } else if (bx == 64) {
    float s = 0.f;
    for (int j = w; j < NB; j += 16) s += wsgq[j * 66 + lane];
    sh[t] = s;
    __syncthreads();
    if (w == 0) {
      float tot = 0.f;
#pragma unroll
      for (int i = 0; i < 16; i++) tot += sh[(i << 6) + lane];
      out[gsr_off + lane] = tot;
    }
  } else {
    float s = 0.f;
    for (int j = t; j < NB; j += 1024) s += wsgq[j * 66 + 64];
    s = wave_sum(s);
    if (lane == 0) sh[w] = s;
    __syncthreads();
    if (t == 0) {
      float tot = 0.f;
#pragma unroll
      for (int i = 0; i < 16; i++) tot += sh[i];
      out[gsr_off + 64] = tot;
    }
  }
}

extern "C" void kernel_launch(void* const* d_in, const int* in_sizes, int n_in,
                              void* d_out, int out_size, void* d_ws,
                              size_t ws_size, hipStream_t stream) {
  (void)n_in; (void)out_size;
  const float* bow   = (const float*)d_in[0];
  const float* seeds = (const float*)d_in[1];
  const float* exp_m = (const float*)d_in[2];
  const float* exp_s = (const float*)d_in[3];
  const float* exp_n = (const float*)d_in[4];
  const float* pi    = (const float*)d_in[5];
  int K = in_sizes[5];          // 64
  int V = in_sizes[1] / K;      // 10000
  float* out = (float*)d_out;
  float* ws = (float*)d_ws;

  int NB = (V + 15) / 16;       // 625 blocks, 16 waves (one v each)
  int gsr_off = 4096 + 2 * V * 64;

  size_t needF = (size_t)NB * 4096 + (size_t)NB * 66 + 64 * 192;
  int useWs = (ws_size >= needF * 4) ? 1 : 0;

  float* wsm  = ws;                          // NB x 4096
  float* wsgq = wsm + (size_t)NB * 4096;     // NB x 66 (gsr 64 + qz)
  float* part = wsgq + (size_t)NB * 66;      // 64 x 192

  int rpb = (V + 63) / 64;
  sums_kernel<<<64, 256, 0, stream>>>(seeds, exp_s, exp_n, part, out, V, rpb,
                                      gsr_off, useWs ? 0 : 1);
  main_kernel<<<NB, 1024, 0, stream>>>(bow, seeds, exp_m, exp_s, exp_n, pi,
                                       part, out, wsm, wsgq, V, useWs, gsr_off);
  if (useWs) {
    reduce_kernel<<<66, 1024, 0, stream>>>(wsm, wsgq, out, NB, gsr_off);
  }
}

// Round 9
// 117.429 us; speedup vs baseline: 1.1530x; 1.0633x over previous
//
#include <hip/hip_runtime.h>
#include <hip/hip_bf16.h>

#define ETA_C  0.1f
#define BETA_C 0.05f
#define MU_C   0.05f
#define MINI_C 1e-6f

typedef __attribute__((ext_vector_type(8))) short short8;
typedef __attribute__((ext_vector_type(4))) float f32x4;

// ---------- DPP wave-64 sum ----------
template<int CTRL, int ROWMASK>
__device__ __forceinline__ float dpp_add(float x) {
  int v = __builtin_amdgcn_update_dpp(0, __float_as_int(x), CTRL, ROWMASK, 0xf, true);
  return x + __int_as_float(v);
}

__device__ __forceinline__ float wave_sum(float x) {
  x = dpp_add<0xB1,  0xF>(x);
  x = dpp_add<0x4E,  0xF>(x);
  x = dpp_add<0x141, 0xF>(x);
  x = dpp_add<0x140, 0xF>(x);
  x = dpp_add<0x142, 0xA>(x);
  x = dpp_add<0x143, 0xC>(x);
  return __int_as_float(__builtin_amdgcn_readlane(__float_as_int(x), 63));
}

__device__ __forceinline__ float rl(float x, int k) {
  return __int_as_float(__builtin_amdgcn_readlane(__float_as_int(x), k));
}

__device__ __forceinline__ short bf16r(float x) {
  unsigned u = __float_as_uint(x);
  u += 0x7fffu + ((u >> 16) & 1u);
  return (short)(u >> 16);
}

// ---------- kernel A: per-block column-sum partials ----------
__global__ __launch_bounds__(256) void sums_kernel(
    const float* __restrict__ seeds, const float* __restrict__ es,
    const float* __restrict__ en, float* __restrict__ part,
    float* __restrict__ out, int V, int rows_per_block, int gsr_off,
    int zeroOut) {
  __shared__ float sh[192];
  int t = threadIdx.x, bx = blockIdx.x;
  if (zeroOut) {
    if (bx < 16) out[(bx << 8) + t] = 0.f;
    else if (bx == 16 && t < 65) out[gsr_off + t] = 0.f;
  }
  if (t < 192) sh[t] = 0.f;
  __syncthreads();
  int k = t & 63, w = t >> 6;
  int v0 = bx * rows_per_block;
  int v1 = min(v0 + rows_per_block, V);
  float s0 = 0.f, s1 = 0.f, s2 = 0.f;
  for (int v = v0 + w; v < v1; v += 4) {
    int idx = (v << 6) + k;
    s0 += seeds[idx]; s1 += es[idx]; s2 += en[idx];
  }
  atomicAdd(&sh[k], s0);
  atomicAdd(&sh[64 + k], s1);
  atomicAdd(&sh[128 + k], s2);
  __syncthreads();
  if (t < 192) part[bx * 192 + t] = sh[t];
}

// ---------- kernel B: main — MFMA for all block matmuls ----------
__global__ __launch_bounds__(1024, 4) void main_kernel(
    const float* __restrict__ bow,   // (B=64, V)
    const float* __restrict__ seeds, // (V, 64)
    const float* __restrict__ exp_m, // (64, 64)
    const float* __restrict__ exp_s, // (V, 64)
    const float* __restrict__ exp_n, // (V, 64)
    const float* __restrict__ pi,    // (64)
    const float* __restrict__ part,  // 64 x 192 column-sum partials
    float* __restrict__ out,
    float* __restrict__ wsm, float* __restrict__ wsgq,
    int V, int useWs, int gsr_off) {
  __shared__ float thF[4096];      // fp32 th [b*64+k]                16 KB
  __shared__ short THbf[4096];     // bf16 th, A-layout [b][k]         8 KB
  __shared__ short THTbf[4096];    // bf16 th^T [k][b]                 8 KB
  __shared__ short TLbf[4096];     // bf16 th*lnth [b][k]              8 KB
  __shared__ short ARRT[1024];     // bf16 arr^T [v][k]                2 KB
  __shared__ short ASVT[1024];     // bf16 (ass+asr)^T [v][k]          2 KB
  __shared__ short ARLT[1024];     // bf16 arr*ln(arr)^T [v][k]        2 KB
  __shared__ short WSRT[2048];     // bf16 [k_out][ws(16v)|wr(16v)]    4 KB
  __shared__ short PKA[2048];      // bf16 [b][cis(16v)|cir(16v)]      4 KB
  __shared__ short CIRT[1024];     // bf16 cirr^T [v][b]               2 KB
  __shared__ float RSL[64 * 17];   // r_sum [b][v]  (reused as NNL)  4.25 KB
  __shared__ float SSL[64 * 17];   // s_sum [b][v]  (reused as red)  4.25 KB
  __shared__ float L0a[64 * 17];   // th*arrl part [b][v]            4.25 KB
  __shared__ float L0b[64 * 17];   // tl*arr  part [b][v]            4.25 KB
  __shared__ float sums_sh[192];
  float* NNL = RSL;                // phase D/E alias (RSL dead after C)
  float* red_gsr = SSL;            // epilogue alias (SSL dead after C)
  float* redq = L0a;               // epilogue alias

  int t = threadIdx.x;
#pragma unroll
  for (int i = 0; i < 4; i++) {
    int idx = t + (i << 10);
    int b = idx >> 6, k = idx & 63;
    float th = exp_m[idx] + ETA_C;
    float lth = __logf(th);
    thF[idx] = th;
    THbf[idx] = bf16r(th);
    THTbf[(k << 6) + b] = bf16r(th);
    TLbf[idx] = bf16r(th * lth);
  }
  if (t < 192) {
    float s = 0.f;
#pragma unroll 8
    for (int j = 0; j < 64; j++) s += part[j * 192 + t];
    sums_sh[t] = s;
  }
  __syncthreads();

  int lane = t & 63, w = t >> 6;
  int v = (blockIdx.x << 4) + w;
  bool active = (v < V);
  int q = lane >> 4, c = lane & 15;

  // ---- phase A: per-v coefficient vectors (lane = k) ----
  float pik = 0.f, omp = 0.f, a_ss = 0.f, a_sr = 0.f, a_rr = 0.f;
  float bowpre = 0.f;
  bool seedRow = false;
  if (active) {
    int rbase = (v << 6) + lane;
    float seed = seeds[rbase];
    float es = exp_s[rbase];
    float en = exp_n[rbase];
    pik = pi[lane];
    float inv_ds = __builtin_amdgcn_rcpf(MU_C * sums_sh[lane] + sums_sh[64 + lane]);
    float inv_dn = __builtin_amdgcn_rcpf(BETA_C * (float)V + sums_sh[128 + lane]);
    float phi_s = (MU_C + es) * inv_ds;
    float phi_n = (BETA_C + en) * inv_dn;
    omp = 1.0f - pik;
    a_ss = seed * phi_s * pik;
    a_sr = seed * phi_n * omp;
    a_rr = (1.0f - seed) * phi_n;
    seedRow = (__ballot(seed > 0.f) != 0ull);
    float wsv = fmaf(pik, a_ss, omp * a_sr);
    float wrv = seedRow ? omp * a_rr : a_rr;
    float arrl = (a_rr > 0.f) ? a_rr * __logf(a_rr) : 0.f;
    ARRT[(w << 6) + lane] = bf16r(a_rr);
    ASVT[(w << 6) + lane] = bf16r(a_ss + a_sr);
    ARLT[(w << 6) + lane] = bf16r(arrl);
    WSRT[(lane << 5) + w] = bf16r(wsv);
    WSRT[(lane << 5) + 16 + w] = bf16r(wrv);
    bowpre = bow[lane * V + v];          // lane = b
  } else {
    ARRT[(w << 6) + lane] = 0;
    ASVT[(w << 6) + lane] = 0;
    ARLT[(w << 6) + lane] = 0;
    WSRT[(lane << 5) + w] = 0;
    WSRT[(lane << 5) + 16 + w] = 0;
  }
  __syncthreads();

  // ---- phase B: RS / SS / L0a / L0b matmuls, one tile-job per wave ----
  {
    int job = w >> 2, mt = w & 3;
    const short* Amat = (job == 3) ? TLbf : THbf;
    const short* Bmat = (job == 0) ? ARRT : (job == 1) ? ASVT
                       : (job == 2) ? ARLT : ARRT;
    float* Cd = (job == 0) ? RSL : (job == 1) ? SSL : (job == 2) ? L0a : L0b;
    f32x4 acc = {0.f, 0.f, 0.f, 0.f};
    int arow = (mt << 4) + c;            // A: m = lane&15
#pragma unroll
    for (int s = 0; s < 2; s++) {
      short8 af = *(const short8*)&Amat[(arow << 6) + (s << 5) + (q << 3)];
      short8 bf = *(const short8*)&Bmat[(c << 6) + (s << 5) + (q << 3)];
      acc = __builtin_amdgcn_mfma_f32_16x16x32_bf16(af, bf, acc, 0, 0, 0);
    }
#pragma unroll
    for (int r = 0; r < 4; r++)
      Cd[((mt << 4) + (q << 2) + r) * 17 + c] = acc[r];
  }
  __syncthreads();

  // ---- phase C: per-v normalization (lane = b) + seed exact path ----
  float acc_s = 0.f, acc_g = 0.f, acc_qk = 0.f, acc_qb = 0.f;
  if (active) {
    float rsv = RSL[lane * 17 + w];
    float ssv = SSL[lane * 17 + w];
    float ivx = __builtin_amdgcn_rcpf(ssv + MINI_C);
    float ivy = __builtin_amdgcn_rcpf(rsv + MINI_C);
    float cis = bowpre * ivx;
    float cirr = bowpre * ivy;
    PKA[(lane << 5) + w] = bf16r(cis);
    PKA[(lane << 5) + 16 + w] = bf16r(cirr);
    CIRT[(w << 6) + lane] = bf16r(cirr);
    if (!seedRow) {
      float Lb = L0a[lane * 17 + w] + L0b[lane * 17 + w];
      float q0 = (bowpre > 0.f) ? ivy : 0.f;
      float q1 = q0 * __logf(ivy);
      acc_qb = fmaf(q0, Lb, q1 * rsv);
      out[4096 + V * 64 + (v << 6) + lane] = 0.f;   // temp_exp_s
    } else {
      float acc_n = 0.f;
      unsigned long long m = __ballot(bowpre > 0.f);
      while (m) {
        int b = __builtin_amdgcn_readfirstlane(__builtin_ctzll(m));
        m &= (m - 1);
        float cb = rl(bowpre, b);
        float is = rl(ivx, b), ir = rl(ivy, b);
        float th = thF[(b << 6) + lane];
        float gss = th * a_ss * is;
        float gsr = th * a_sr * is;
        float grr = th * a_rr * ir;
        float gnr = gsr + grr;
        float gamma = fmaf(pik, gss, omp * gnr);
        acc_n = fmaf(gnr, cb, acc_n);
        acc_s = fmaf(gss, cb, acc_s);
        acc_g += gsr;
        acc_qk = fmaf(gamma, __logf(gamma + MINI_C), acc_qk);
      }
      out[4096 + (v << 6) + lane] = acc_n;
      out[4096 + V * 64 + (v << 6) + lane] = acc_s;
    }
  } else {
    PKA[(lane << 5) + w] = 0;
    PKA[(lane << 5) + 16 + w] = 0;
    CIRT[(w << 6) + lane] = 0;
  }
  __syncthreads();

  // ---- phase D: P matmul (temp_exp_m partial) + N matmul (waves 12-15) ----
  {
    int tm = w >> 2, tn = w & 3;
    f32x4 acc = {0.f, 0.f, 0.f, 0.f};
    short8 af = *(const short8*)&PKA[(((tm << 4) + c) << 5) + (q << 3)];
    short8 bf = *(const short8*)&WSRT[(((tn << 4) + c) << 5) + (q << 3)];
    acc = __builtin_amdgcn_mfma_f32_16x16x32_bf16(af, bf, acc, 0, 0, 0);
#pragma unroll
    for (int r = 0; r < 4; r++) {
      int brow = (tm << 4) + (q << 2) + r;
      int kcol = (tn << 4) + c;
      float val = acc[r] * thF[(brow << 6) + kcol];
      if (useWs) wsm[blockIdx.x * 4096 + (brow << 6) + kcol] = val;
      else atomicAdd(&out[(brow << 6) + kcol], val);
    }
    if (w >= 12) {
      int mt = w - 12;
      f32x4 an = {0.f, 0.f, 0.f, 0.f};
#pragma unroll
      for (int s = 0; s < 2; s++) {
        short8 a2 = *(const short8*)&THTbf[(((mt << 4) + c) << 6) + (s << 5) + (q << 3)];
        short8 b2 = *(const short8*)&CIRT[(c << 6) + (s << 5) + (q << 3)];
        an = __builtin_amdgcn_mfma_f32_16x16x32_bf16(a2, b2, an, 0, 0, 0);
      }
#pragma unroll
      for (int r = 0; r < 4; r++)
        NNL[((mt << 4) + (q << 2) + r) * 17 + c] = an[r];
    }
  }
  __syncthreads();

  // ---- phase E: temp_exp_n for non-seed rows (lane = k) ----
  if (active && !seedRow)
    out[4096 + (v << 6) + lane] = a_rr * NNL[lane * 17 + w];

  red_gsr[t] = acc_g;
  float qzw = wave_sum(acc_qk + acc_qb);
  if (lane == 0) redq[w] = qzw;
  __syncthreads();

  if (w == 0) {
    float g = 0.f;
#pragma unroll
    for (int j = 0; j < 16; j++) g += red_gsr[(j << 6) + lane];
    if (useWs) wsgq[blockIdx.x * 66 + lane] = g;
    else if (g != 0.f) atomicAdd(&out[gsr_off + lane], g);
    if (t == 0) {
      float qs = 0.f;
#pragma unroll
      for (int j = 0; j < 16; j++) qs += redq[j];
      if (useWs) wsgq[blockIdx.x * 66 + 64] = qs;
      else atomicAdd(&out[gsr_off + 64], qs);
    }
  }
}

// ---------- kernel C: parallel reduce of per-block partials ----------
__global__ __launch_bounds__(1024) void reduce_kernel(
    const float* __restrict__ wsm, const float* __restrict__ wsgq,
    float* __restrict__ out, int NB, int gsr_off) {
  __shared__ float sh[1024];
  int t = threadIdx.x, lane = t & 63, w = t >> 6, bx = blockIdx.x;
  if (bx < 64) {
    int e = (bx << 6) + lane;
    float s0 = 0.f, s1 = 0.f, s2 = 0.f, s3 = 0.f;
    int j = w;
    for (; j + 48 < NB; j += 64) {
      s0 += wsm[(size_t)(j)      * 4096 + e];
      s1 += wsm[(size_t)(j + 16) * 4096 + e];
      s2 += wsm[(size_t)(j + 32) * 4096 + e];
      s3 += wsm[(size_t)(j + 48) * 4096 + e];
    }
    for (; j < NB; j += 16) s0 += wsm[(size_t)j * 4096 + e];
    sh[t] = (s0 + s1) + (s2 + s3);
    __syncthreads();
    if (w == 0) {
      float tot = 0.f;
#pragma unroll
      for (int i = 0; i < 16; i++) tot += sh[(i << 6) + lane];
      out[e] = tot;
    }
  } else if (bx == 64) {
    float s = 0.f;
    for (int j = w; j < NB; j += 16) s += wsgq[j * 66 + lane];
    sh[t] = s;
    __syncthreads();
    if (w == 0) {
      float tot = 0.f;
#pragma unroll
      for (int i = 0; i < 16; i++) tot += sh[(i << 6) + lane];
      out[gsr_off + lane] = tot;
    }
  } else {
    float s = 0.f;
    for (int j = t; j < NB; j += 1024) s += wsgq[j * 66 + 64];
    s = wave_sum(s);
    if (lane == 0) sh[w] = s;
    __syncthreads();
    if (t == 0) {
      float tot = 0.f;
#pragma unroll
      for (int i = 0; i < 16; i++) tot += sh[i];
      out[gsr_off + 64] = tot;
    }
  }
}

extern "C" void kernel_launch(void* const* d_in, const int* in_sizes, int n_in,
                              void* d_out, int out_size, void* d_ws,
                              size_t ws_size, hipStream_t stream) {
  (void)n_in; (void)out_size;
  const float* bow   = (const float*)d_in[0];
  const float* seeds = (const float*)d_in[1];
  const float* exp_m = (const float*)d_in[2];
  const float* exp_s = (const float*)d_in[3];
  const float* exp_n = (const float*)d_in[4];
  const float* pi    = (const float*)d_in[5];
  int K = in_sizes[5];          // 64
  int V = in_sizes[1] / K;      // 10000
  float* out = (float*)d_out;
  float* ws = (float*)d_ws;

  int NB = (V + 15) / 16;       // 625 blocks, 16 waves (one v each)
  int gsr_off = 4096 + 2 * V * 64;

  size_t needF = (size_t)NB * 4096 + (size_t)NB * 66 + 64 * 192;
  int useWs = (ws_size >= needF * 4) ? 1 : 0;

  float* wsm  = ws;                          // NB x 4096
  float* wsgq = wsm + (size_t)NB * 4096;     // NB x 66 (gsr 64 + qz)
  float* part = wsgq + (size_t)NB * 66;      // 64 x 192

  int rpb = (V + 63) / 64;
  sums_kernel<<<64, 256, 0, stream>>>(seeds, exp_s, exp_n, part, out, V, rpb,
                                      gsr_off, useWs ? 0 : 1);
  main_kernel<<<NB, 1024, 0, stream>>>(bow, seeds, exp_m, exp_s, exp_n, pi,
                                       part, out, wsm, wsgq, V, useWs, gsr_off);
  if (useWs) {
    reduce_kernel<<<66, 1024, 0, stream>>>(wsm, wsgq, out, NB, gsr_off);
  }
}